// Round 15
// baseline (202.735 us; speedup 1.0000x reference)
//
#include <hip/hip_runtime.h>
#include <stdint.h>

typedef __attribute__((ext_vector_type(8))) short bf16x8;
typedef __attribute__((ext_vector_type(4))) float f32x4;
typedef __attribute__((ext_vector_type(8))) unsigned short u16x8;
typedef __attribute__((ext_vector_type(4))) unsigned short u16x4;
typedef unsigned short ushort_t;

#define MFMA16(a, b, c) __builtin_amdgcn_mfma_f32_16x16x32_bf16((a), (b), (c), 0, 0, 0)
#define GLDS(g, l)                                                              \
  __builtin_amdgcn_global_load_lds((const __attribute__((address_space(1))) void*)(g), \
                                   (__attribute__((address_space(3))) void*)(l), 16, 0, 0)

static __device__ __forceinline__ unsigned short f2bf(float x) {
  unsigned int u = __builtin_bit_cast(unsigned int, x);
  u += 0x7fff + ((u >> 16) & 1);  // RNE
  return (unsigned short)(u >> 16);
}

static __device__ __forceinline__ unsigned cvtpk_bf16(float lo, float hi) {
  unsigned r;
  asm("v_cvt_pk_bf16_f32 %0, %1, %2" : "=v"(r) : "v"(lo), "v"(hi));
  return r;
}

// ---------------------------------------------------------------- fused prep:
// blocks [0,12288): cvt q/k/v ; [12288,14336): cvt W* ; [14336,14592): rope table
__global__ __launch_bounds__(256)
void prep(const float* __restrict__ q, const float* __restrict__ k,
          const float* __restrict__ v, const float* __restrict__ Wq,
          const float* __restrict__ Wk, const float* __restrict__ Wv,
          const float* __restrict__ Wo, ushort_t* __restrict__ oq,
          ushort_t* __restrict__ ok, ushort_t* __restrict__ ov,
          ushort_t* __restrict__ oWq, ushort_t* __restrict__ oWk,
          ushort_t* __restrict__ oWv, ushort_t* __restrict__ oWo,
          float2* __restrict__ tab) {
  const int bid = blockIdx.x;
  if (bid < 14336) {
    const float* in;
    ushort_t* out;
    int lb;
    if (bid < 12288) {
      in = bid < 4096 ? q : (bid < 8192 ? k : v);
      out = bid < 4096 ? oq : (bid < 8192 ? ok : ov);
      lb = bid & 4095;
    } else {
      const int r = bid - 12288;
      in = r < 512 ? Wq : (r < 1024 ? Wk : (r < 1536 ? Wv : Wo));
      out = r < 512 ? oWq : (r < 1024 ? oWk : (r < 1536 ? oWv : oWo));
      lb = r & 511;
    }
    const size_t i = ((size_t)lb * 256 + threadIdx.x) * 8;
    f32x4 a = *(const f32x4*)(in + i);
    f32x4 b = *(const f32x4*)(in + i + 4);
    u16x8 o;
    o[0] = f2bf(a[0]); o[1] = f2bf(a[1]); o[2] = f2bf(a[2]); o[3] = f2bf(a[3]);
    o[4] = f2bf(b[0]); o[5] = f2bf(b[1]); o[6] = f2bf(b[2]); o[7] = f2bf(b[3]);
    *(u16x8*)(out + i) = o;
  } else {
    const int i = (bid - 14336) * 256 + threadIdx.x;  // 0..65535
    const int l = i >> 5, f = i & 31;
    float inv = powf(10000.0f, -(float)f / 32.0f);
    float ang = (float)l * inv;
    float s, c;
    sincosf(ang, &s, &c);
    tab[i] = make_float2(c, s);
  }
}

// ---------------------------------------------------------------- fused QKV GEMM
// NEW: 256x128 tile, 8 waves (4Mx2N), BK=64, TRIPLE-buffered LDS (144KB, 1 blk/CU),
// counted-vmcnt pipeline (derived ledger, provably race-free):
//   stage T+2 -> buffer consumed at iter T-1; end-of-iter vmcnt(6) retires T+1;
//   raw s_barrier (no vmcnt(0) drain); sched_barrier(0) pins (rule 18).
// LDS XOR-swizzle pair (attn-verified): source sc=(s^(s>>3))&7, read ^((row&7)<<4).
// Per-wave fragment indexing identical to R14-verified code.
// z=0: q -> Qh rope, scale=0.125 ; z=1: k -> Kh rope ; z=2: v -> VhT direct.
__global__ __launch_bounds__(512, 1)
void gemm_qkv(const ushort_t* __restrict__ qb, const ushort_t* __restrict__ kb2,
              const ushort_t* __restrict__ vb, const ushort_t* __restrict__ Wqb,
              const ushort_t* __restrict__ Wkb, const ushort_t* __restrict__ Wvb,
              const float* __restrict__ bq, const float* __restrict__ bk,
              const float* __restrict__ bv, ushort_t* __restrict__ Qh,
              ushort_t* __restrict__ Kh, ushort_t* __restrict__ VhT,
              const float2* __restrict__ rope) {
  constexpr int K = 1024;
  constexpr int NT = K / 64;            // 16 K-tiles
  __shared__ ushort_t As[3][256 * 64];  // 96 KB
  __shared__ ushort_t Bs[3][128 * 64];  // 48 KB

  const int b = blockIdx.x;  // 768 blocks: 8 xcd x 8 bx x 4 byh x 3 z
  const int xcd = b & 7, i2 = b >> 3;
  const int bx = i2 & 7;
  const int byh = (i2 >> 3) & 3;
  const int z = i2 >> 5;
  const int by = byh * 8 + xcd;  // same-XCD blocks sweep bx at fixed (byh,z): A-panel L2 reuse

  const ushort_t* Am = z == 0 ? qb : (z == 1 ? kb2 : vb);
  const ushort_t* Wm = z == 0 ? Wqb : (z == 1 ? Wkb : Wvb);
  const float* bias = z == 0 ? bq : (z == 1 ? bk : bv);
  const float scale = z == 0 ? 0.125f : 1.0f;  // 1/sqrt(64)

  const int t = threadIdx.x;            // 0..511
  const int lane = t & 63, w = t >> 6;  // 8 waves
  const int lq = lane & 15, lg = lane >> 4;
  const int wr = w >> 1, wc = w & 1;    // 4(M) x 2(N) wave grid, 64x64 out each
  const int row0 = by * 256;
  const int col0 = bx * 128;

  auto STAGE = [&](int buf, int kt) {  // 6 gload_lds per thread (4 A + 2 B)
#pragma unroll
    for (int r = 0; r < 4; ++r) {
      const int s = r * 512 + t;
      const int sc = (s ^ (s >> 3)) & 7;  // pre-swizzled source chunk
      GLDS(Am + (size_t)(row0 + (s >> 3)) * K + kt * 64 + sc * 8,
           &As[buf][(r * 512 + w * 64) * 8]);
    }
#pragma unroll
    for (int r = 0; r < 2; ++r) {
      const int s = r * 512 + t;
      const int sc = (s ^ (s >> 3)) & 7;
      GLDS(Wm + (size_t)(col0 + (s >> 3)) * K + kt * 64 + sc * 8,
           &Bs[buf][(r * 512 + w * 64) * 8]);
    }
  };

  f32x4 acc[4][4] = {};
  STAGE(0, 0);
  STAGE(1, 1);
  asm volatile("s_waitcnt vmcnt(6)" ::: "memory");  // T0 landed (T1 in flight)
  __builtin_amdgcn_sched_barrier(0);
  __builtin_amdgcn_s_barrier();
  __builtin_amdgcn_sched_barrier(0);

  for (int kt = 0; kt < NT; ++kt) {
    const int buf = kt % 3;
    if (kt + 2 < NT) STAGE((kt + 2) % 3, kt + 2);  // target consumed at iter kt-1
    const char* Ab = (const char*)&As[buf][0];
    const char* Bb = (const char*)&Bs[buf][0];
#pragma unroll
    for (int kc = 0; kc < 2; ++kc) {
      bf16x8 af[4], bfr[4];
#pragma unroll
      for (int mf = 0; mf < 4; ++mf) {
        const int ar = wr * 64 + mf * 16 + lq;
        af[mf] = *(const bf16x8*)(Ab + ((ar * 128 + kc * 64 + lg * 16) ^ ((ar & 7) << 4)));
      }
#pragma unroll
      for (int nf = 0; nf < 4; ++nf) {
        const int br = wc * 64 + nf * 16 + lq;
        bfr[nf] = *(const bf16x8*)(Bb + ((br * 128 + kc * 64 + lg * 16) ^ ((br & 7) << 4)));
      }
      __builtin_amdgcn_s_setprio(1);
#pragma unroll
      for (int mf = 0; mf < 4; ++mf)
#pragma unroll
        for (int nf = 0; nf < 4; ++nf)
          acc[mf][nf] = MFMA16(af[mf], bfr[nf], acc[mf][nf]);
      __builtin_amdgcn_s_setprio(0);
    }
    // ledger: outstanding = T+1(6) + T+2(6 if staged); retire T+1 before next iter
    if (kt <= NT - 3) {
      asm volatile("s_waitcnt vmcnt(6)" ::: "memory");
    } else if (kt == NT - 2) {
      asm volatile("s_waitcnt vmcnt(0)" ::: "memory");
    }
    if (kt < NT - 1) {
      __builtin_amdgcn_sched_barrier(0);
      __builtin_amdgcn_s_barrier();
      __builtin_amdgcn_sched_barrier(0);
    }
  }

  float bvv[4];
#pragma unroll
  for (int nf = 0; nf < 4; ++nf) bvv[nf] = bias[col0 + wc * 64 + nf * 16 + lq];

#pragma unroll
  for (int mf = 0; mf < 4; ++mf) {
#pragma unroll
    for (int nf = 0; nf < 4; ++nf) {
      const int col = col0 + wc * 64 + nf * 16 + lq;
      const int h = col >> 6, d = col & 63;
      if (z < 2) {  // rope scatter to [B,H,L,64]
        ushort_t* o = z == 0 ? Qh : Kh;
#pragma unroll
        for (int u = 0; u < 4; ++u) {
          const int row = row0 + wr * 64 + mf * 16 + 4 * lg + u;
          const int bb = row >> 11, l = row & 2047;
          float val = acc[mf][nf][u] + bvv[nf];
          float2 cs = rope[l * 32 + (d >> 1)];
          float p = __shfl_xor(val, 1, 64);
          val = ((d & 1) ? (val * cs.x + p * cs.y) : (val * cs.x - p * cs.y)) * scale;
          o[(((size_t)bb * 16 + h) * 2048 + l) * 64 + d] = f2bf(val);
        }
      } else {  // V^T direct: VhT[(bh*64 + d)*2048 + l]
        const int row = row0 + wr * 64 + mf * 16 + 4 * lg;
        const int bb = row >> 11, l0 = row & 2047;
        u16x4 o;
#pragma unroll
        for (int u = 0; u < 4; ++u) o[u] = f2bf(acc[mf][nf][u] + bvv[nf]);
        *(u16x4*)(VhT + (((size_t)bb * 16 + h) * 64 + d) * 2048 + l0) = o;
      }
    }
  }
}

// ---------------------------------------------------------------- Wo GEMM -> f32 out
// R14-verified (256,4). Untouched.
__global__ __launch_bounds__(256, 4)
void gemm_out(const ushort_t* __restrict__ Am, const ushort_t* __restrict__ Wm,
              const float* __restrict__ bias, float* __restrict__ outp) {
  constexpr int K = 1024;
  __shared__ ushort_t As[128 * 64];
  __shared__ ushort_t Bs[128 * 64];

  const int b = blockIdx.x;
  const int xcd = b & 7, i2 = b >> 3;
  const int bx = i2 & 7;
  const int by = ((i2 >> 3) & 7) * 8 + xcd;

  const int t = threadIdx.x;
  const int lane = t & 63, w = t >> 6;
  const int lq = lane & 15, lg = lane >> 4;
  const int wr = w >> 1, wc = w & 1;
  const int row0 = by * 128;
  const int col0 = bx * 128;

  f32x4 acc[4][4] = {};
  for (int kt = 0; kt < K / 64; ++kt) {
    __syncthreads();
#pragma unroll
    for (int it = 0; it < 4; ++it) {
      const int s = it * 256 + t;
      const int ldsoff = (it * 256 + w * 64) * 8;
      GLDS(Am + (size_t)(row0 + (s >> 3)) * K + kt * 64 + (s & 7) * 8, &As[ldsoff]);
      GLDS(Wm + (size_t)(col0 + (s >> 3)) * K + kt * 64 + (s & 7) * 8, &Bs[ldsoff]);
    }
    __syncthreads();
#pragma unroll
    for (int kc = 0; kc < 2; ++kc) {
      bf16x8 af[4], bfr[4];
#pragma unroll
      for (int mf = 0; mf < 4; ++mf)
        af[mf] = *(const bf16x8*)(&As[(wr * 64 + mf * 16 + lq) * 64 + kc * 32 + lg * 8]);
#pragma unroll
      for (int nf = 0; nf < 4; ++nf)
        bfr[nf] = *(const bf16x8*)(&Bs[(wc * 64 + nf * 16 + lq) * 64 + kc * 32 + lg * 8]);
#pragma unroll
      for (int mf = 0; mf < 4; ++mf)
#pragma unroll
        for (int nf = 0; nf < 4; ++nf)
          acc[mf][nf] = MFMA16(af[mf], bfr[nf], acc[mf][nf]);
    }
  }

  float bvv[4];
#pragma unroll
  for (int nf = 0; nf < 4; ++nf) bvv[nf] = bias[col0 + wc * 64 + nf * 16 + lq];

#pragma unroll
  for (int mf = 0; mf < 4; ++mf) {
#pragma unroll
    for (int nf = 0; nf < 4; ++nf) {
      const int col = col0 + wc * 64 + nf * 16 + lq;
#pragma unroll
      for (int u = 0; u < 4; ++u) {
        const int row = row0 + wr * 64 + mf * 16 + 4 * lg + u;
        outp[(size_t)row * 1024 + col] = acc[mf][nf][u] + bvv[nf];
      }
    }
  }
}

// ---------------------------------------------------------------- flash attention (causal)
// R10/R14-verified kernel. Untouched.
__global__ __launch_bounds__(256, 4)
void attn_fwd(const ushort_t* __restrict__ Qh, const ushort_t* __restrict__ Kh,
              const ushort_t* __restrict__ VhT, ushort_t* __restrict__ attn) {
  constexpr int L = 2048;
  __shared__ __align__(16) char KV[2][16384];  // [buf][ K 8KB | V^T 8KB ], XOR-swizzled
  __shared__ __align__(16) char Pl[4][2048];   // per-wave P [16 q][64 kv] bf16, XOR-swizzled
  const int t = threadIdx.x;
  const int lane = t & 63, w = t >> 6;
  const int lq = lane & 15, lg = lane >> 4;

  const int fid = blockIdx.y * 16 + blockIdx.x;  // XCD swizzle: one bh per XCD group
  const int bh = (fid & 7) * 8 + (fid >> 7);
  const int i = (fid >> 3) & 15;
  const int lo = i, hi = 31 - i, nt = 32 - i;
  const int qlo = lo * 64 + w * 16 + lq;
  const int qhi = hi * 64 + w * 16 + lq;

  bf16x8 qfl[2], qfh[2];
  {
    const ushort_t* p = Qh + ((size_t)bh * L + qlo) * 64 + lg * 8;
    qfl[0] = *(const bf16x8*)p;
    qfl[1] = *(const bf16x8*)(p + 32);
    const ushort_t* p2 = Qh + ((size_t)bh * L + qhi) * 64 + lg * 8;
    qfh[0] = *(const bf16x8*)p2;
    qfh[1] = *(const bf16x8*)(p2 + 32);
  }

  float ml = -1e30f, ll = 0.0f, mh = -1e30f, lh = 0.0f;
  f32x4 otl[4] = {}, oth[4] = {};
  char* const pw = Pl[w];

  auto STAGE = [&](int bb, int kb) {
    const int kv0 = kb * 64;
#pragma unroll
    for (int it = 0; it < 2; ++it) {
      const int s = it * 256 + t;
      const int r = s >> 3;
      const int sc = (s ^ r) & 7;  // inverse swizzle on the global source (G21)
      char* base = KV[bb] + (it * 256 + w * 64) * 16;
      GLDS(Kh + ((size_t)bh * L + kv0 + r) * 64 + sc * 8, base);
      GLDS(VhT + ((size_t)bh * 64 + r) * L + kv0 + sc * 8, base + 8192);
    }
  };

  auto TILE = [&](int bb, int kb, int diagkb, int qrow, const bf16x8* qf, float& m,
                  float& lsum, f32x4* ot) {
    const char* Kb = KV[bb];
    const char* Vb = KV[bb] + 8192;
    f32x4 st[4];
    __builtin_amdgcn_s_setprio(1);
#pragma unroll
    for (int kf = 0; kf < 4; ++kf) {
      f32x4 c = {};
#pragma unroll
      for (int kc = 0; kc < 2; ++kc) {
        const int r = kf * 16 + lq;
        const int byte = (r * 128 + kc * 64 + lg * 16) ^ ((r & 7) << 4);
        c = MFMA16(*(const bf16x8*)(Kb + byte), qf[kc], c);
      }
      st[kf] = c;
    }
    __builtin_amdgcn_s_setprio(0);
    if (kb == diagkb) {
      const int kv0 = kb * 64;
#pragma unroll
      for (int kf = 0; kf < 4; ++kf)
#pragma unroll
        for (int u = 0; u < 4; ++u)
          if (kv0 + kf * 16 + 4 * lg + u > qrow) st[kf][u] = -1e30f;
    }
    // row max (q = lq), reduce across lg groups
    float pmax = st[0][0];
#pragma unroll
    for (int kf = 0; kf < 4; ++kf)
#pragma unroll
      for (int u = 0; u < 4; ++u) pmax = fmaxf(pmax, st[kf][u]);
    pmax = fmaxf(pmax, __shfl_xor(pmax, 16, 64));
    pmax = fmaxf(pmax, __shfl_xor(pmax, 32, 64));
    // defer-max (T13): skip O/l rescale while max growth < 11
    if (!__all(pmax <= m + 11.0f)) {
      const float mn = fmaxf(m, pmax);
      const float c2 = __expf(m - mn);
      lsum *= c2;
#pragma unroll
      for (int df = 0; df < 4; ++df) ot[df] *= c2;
      m = mn;
    }
    float psum = 0.0f;
#pragma unroll
    for (int kf = 0; kf < 4; ++kf) {
      const float p0 = __expf(st[kf][0] - m);
      const float p1 = __expf(st[kf][1] - m);
      const float p2 = __expf(st[kf][2] - m);
      const float p3 = __expf(st[kf][3] - m);
      psum += (p0 + p1) + (p2 + p3);
      uint2 pk;
      pk.x = cvtpk_bf16(p0, p1);
      pk.y = cvtpk_bf16(p2, p3);
      const int byte = (lq * 128 + kf * 32 + lg * 8) ^ ((lq & 7) << 4);
      *(uint2*)(pw + byte) = pk;
    }
    psum += __shfl_xor(psum, 16, 64);
    psum += __shfl_xor(psum, 32, 64);
    lsum += psum;
    asm volatile("s_waitcnt lgkmcnt(0)" ::: "memory");
    // O^T[d][q] += V^T . P^T
    __builtin_amdgcn_s_setprio(1);
#pragma unroll
    for (int df = 0; df < 4; ++df) {
#pragma unroll
      for (int kc = 0; kc < 2; ++kc) {
        const int r = df * 16 + lq;
        const int byte = (r * 128 + kc * 64 + lg * 16) ^ ((r & 7) << 4);
        const int pbyte = (lq * 128 + kc * 64 + lg * 16) ^ ((lq & 7) << 4);
        ot[df] = MFMA16(*(const bf16x8*)(Vb + byte), *(const bf16x8*)(pw + pbyte), ot[df]);
      }
    }
    __builtin_amdgcn_s_setprio(0);
  };

  STAGE(0, 0);
  __syncthreads();
  int cur = 0;
  for (int kb = 0; kb < nt; ++kb) {
    if (kb + 1 < nt) STAGE(cur ^ 1, kb + 1);  // prefetch overlaps both tiles' compute
    TILE(cur, kb, hi, qhi, qfh, mh, lh, oth);
    if (kb <= lo) TILE(cur, kb, lo, qlo, qfl, ml, ll, otl);
    __syncthreads();
    cur ^= 1;
  }

  const int b = bh >> 4, h = bh & 15;
  {
    const float inv = 1.0f / lh;
#pragma unroll
    for (int df = 0; df < 4; ++df) {
      u16x4 o;
#pragma unroll
      for (int u = 0; u < 4; ++u) o[u] = f2bf(oth[df][u] * inv);
      *(u16x4*)(attn + ((size_t)b * L + qhi) * 1024 + h * 64 + df * 16 + 4 * lg) = o;
    }
  }
  {
    const float inv = 1.0f / ll;
#pragma unroll
    for (int df = 0; df < 4; ++df) {
      u16x4 o;
#pragma unroll
      for (int u = 0; u < 4; ++u) o[u] = f2bf(otl[df][u] * inv);
      *(u16x4*)(attn + ((size_t)b * L + qlo) * 1024 + h * 64 + df * 16 + 4 * lg) = o;
    }
  }
}

// ---------------------------------------------------------------- launcher
extern "C" void kernel_launch(void* const* d_in, const int* in_sizes, int n_in,
                              void* d_out, int out_size, void* d_ws, size_t ws_size,
                              hipStream_t stream) {
  const float* q = (const float*)d_in[0];
  const float* k = (const float*)d_in[1];
  const float* v = (const float*)d_in[2];
  const float* Wq = (const float*)d_in[3];
  const float* bq = (const float*)d_in[4];
  const float* Wk = (const float*)d_in[5];
  const float* bk = (const float*)d_in[6];
  const float* Wv = (const float*)d_in[7];
  const float* bv = (const float*)d_in[8];
  const float* Wo = (const float*)d_in[9];
  const float* bo = (const float*)d_in[10];

  char* ws = (char*)d_ws;
  const size_t MB = 1ull << 20;
  ushort_t* qb = (ushort_t*)(ws + 0 * MB);    // 16MB (reused as attn after Q GEMM)
  ushort_t* kb = (ushort_t*)(ws + 16 * MB);   // 16MB
  ushort_t* vb = (ushort_t*)(ws + 32 * MB);   // 16MB
  ushort_t* Wqb = (ushort_t*)(ws + 48 * MB);  // 2MB
  ushort_t* Wkb = (ushort_t*)(ws + 50 * MB);  // 2MB
  ushort_t* Wvb = (ushort_t*)(ws + 52 * MB);  // 2MB
  ushort_t* Wob = (ushort_t*)(ws + 54 * MB);  // 2MB
  float2* rope = (float2*)(ws + 56 * MB);     // 512KB
  ushort_t* Qh = (ushort_t*)(ws + 57 * MB);   // 16MB
  ushort_t* Kh = (ushort_t*)(ws + 73 * MB);   // 16MB
  ushort_t* VhT = (ushort_t*)(ws + 89 * MB);  // 16MB
  ushort_t* attnb = qb;                       // alias: qb dead after fused QKV GEMM

  prep<<<14592, 256, 0, stream>>>(q, k, v, Wq, Wk, Wv, Wo, qb, kb, vb, Wqb, Wkb, Wvb,
                                  Wob, rope);

  gemm_qkv<<<768, 512, 0, stream>>>(qb, kb, vb, Wqb, Wkb, Wvb, bq, bk, bv, Qh, Kh, VhT,
                                    rope);

  attn_fwd<<<dim3(16, 64), 256, 0, stream>>>(Qh, Kh, VhT, attnb);

  gemm_out<<<512, 256, 0, stream>>>(attnb, Wob, bo, (float*)d_out);

  (void)in_sizes; (void)n_in; (void)out_size; (void)ws_size;
}

// Round 16
// 191.639 us; speedup vs baseline: 1.0579x; 1.0579x over previous
//
#include <hip/hip_runtime.h>
#include <stdint.h>

typedef __attribute__((ext_vector_type(8))) short bf16x8;
typedef __attribute__((ext_vector_type(4))) float f32x4;
typedef __attribute__((ext_vector_type(8))) unsigned short u16x8;
typedef __attribute__((ext_vector_type(4))) unsigned short u16x4;
typedef unsigned short ushort_t;

#define MFMA16(a, b, c) __builtin_amdgcn_mfma_f32_16x16x32_bf16((a), (b), (c), 0, 0, 0)
#define GLDS(g, l)                                                              \
  __builtin_amdgcn_global_load_lds((const __attribute__((address_space(1))) void*)(g), \
                                   (__attribute__((address_space(3))) void*)(l), 16, 0, 0)

static __device__ __forceinline__ unsigned short f2bf(float x) {
  unsigned int u = __builtin_bit_cast(unsigned int, x);
  u += 0x7fff + ((u >> 16) & 1);  // RNE
  return (unsigned short)(u >> 16);
}

static __device__ __forceinline__ unsigned cvtpk_bf16(float lo, float hi) {
  unsigned r;
  asm("v_cvt_pk_bf16_f32 %0, %1, %2" : "=v"(r) : "v"(lo), "v"(hi));
  return r;
}

// ---------------------------------------------------------------- fused prep:
// blocks [0,12288): cvt q/k/v ; [12288,14336): cvt W* ; [14336,14592): rope table
__global__ __launch_bounds__(256)
void prep(const float* __restrict__ q, const float* __restrict__ k,
          const float* __restrict__ v, const float* __restrict__ Wq,
          const float* __restrict__ Wk, const float* __restrict__ Wv,
          const float* __restrict__ Wo, ushort_t* __restrict__ oq,
          ushort_t* __restrict__ ok, ushort_t* __restrict__ ov,
          ushort_t* __restrict__ oWq, ushort_t* __restrict__ oWk,
          ushort_t* __restrict__ oWv, ushort_t* __restrict__ oWo,
          float2* __restrict__ tab) {
  const int bid = blockIdx.x;
  if (bid < 14336) {
    const float* in;
    ushort_t* out;
    int lb;
    if (bid < 12288) {
      in = bid < 4096 ? q : (bid < 8192 ? k : v);
      out = bid < 4096 ? oq : (bid < 8192 ? ok : ov);
      lb = bid & 4095;
    } else {
      const int r = bid - 12288;
      in = r < 512 ? Wq : (r < 1024 ? Wk : (r < 1536 ? Wv : Wo));
      out = r < 512 ? oWq : (r < 1024 ? oWk : (r < 1536 ? oWv : oWo));
      lb = r & 511;
    }
    const size_t i = ((size_t)lb * 256 + threadIdx.x) * 8;
    f32x4 a = *(const f32x4*)(in + i);
    f32x4 b = *(const f32x4*)(in + i + 4);
    u16x8 o;
    o[0] = f2bf(a[0]); o[1] = f2bf(a[1]); o[2] = f2bf(a[2]); o[3] = f2bf(a[3]);
    o[4] = f2bf(b[0]); o[5] = f2bf(b[1]); o[6] = f2bf(b[2]); o[7] = f2bf(b[3]);
    *(u16x8*)(out + i) = o;
  } else {
    const int i = (bid - 14336) * 256 + threadIdx.x;  // 0..65535
    const int l = i >> 5, f = i & 31;
    float inv = powf(10000.0f, -(float)f / 32.0f);
    float ang = (float)l * inv;
    float s, c;
    sincosf(ang, &s, &c);
    tab[i] = make_float2(c, s);
  }
}

// ---------------------------------------------------------------- fused QKV GEMM
// R14-verified: single-buffered m97 structure; XCD-aware remap; (256,4)
// (VGPR 60, 4 blocks/CU, Occupancy 34%, 77.4us).
// z=0: q -> Qh rope, scale=0.125 ; z=1: k -> Kh rope ; z=2: v -> VhT direct.
__global__ __launch_bounds__(256, 4)
void gemm_qkv(const ushort_t* __restrict__ qb, const ushort_t* __restrict__ kb2,
              const ushort_t* __restrict__ vb, const ushort_t* __restrict__ Wqb,
              const ushort_t* __restrict__ Wkb, const ushort_t* __restrict__ Wvb,
              const float* __restrict__ bq, const float* __restrict__ bk,
              const float* __restrict__ bv, ushort_t* __restrict__ Qh,
              ushort_t* __restrict__ Kh, ushort_t* __restrict__ VhT,
              const float2* __restrict__ rope) {
  constexpr int K = 1024;
  __shared__ ushort_t As[128 * 64];
  __shared__ ushort_t Bs[128 * 64];

  const int b = blockIdx.x;
  const int xcd = b & 7, i2 = b >> 3;
  const int bx = i2 & 7;
  const int by = ((i2 >> 3) & 7) * 8 + xcd;
  const int z = i2 >> 6;

  const ushort_t* Am = z == 0 ? qb : (z == 1 ? kb2 : vb);
  const ushort_t* Wm = z == 0 ? Wqb : (z == 1 ? Wkb : Wvb);
  const float* bias = z == 0 ? bq : (z == 1 ? bk : bv);
  const float scale = z == 0 ? 0.125f : 1.0f;  // 1/sqrt(64)

  const int t = threadIdx.x;
  const int lane = t & 63, w = t >> 6;
  const int lq = lane & 15, lg = lane >> 4;
  const int wr = w >> 1, wc = w & 1;
  const int row0 = by * 128;
  const int col0 = bx * 128;

  f32x4 acc[4][4] = {};
  for (int kt = 0; kt < K / 64; ++kt) {
    __syncthreads();
#pragma unroll
    for (int it = 0; it < 4; ++it) {
      const int s = it * 256 + t;
      const int ldsoff = (it * 256 + w * 64) * 8;
      GLDS(Am + (size_t)(row0 + (s >> 3)) * K + kt * 64 + (s & 7) * 8, &As[ldsoff]);
      GLDS(Wm + (size_t)(col0 + (s >> 3)) * K + kt * 64 + (s & 7) * 8, &Bs[ldsoff]);
    }
    __syncthreads();
#pragma unroll
    for (int kc = 0; kc < 2; ++kc) {
      bf16x8 af[4], bfr[4];
#pragma unroll
      for (int mf = 0; mf < 4; ++mf)
        af[mf] = *(const bf16x8*)(&As[(wr * 64 + mf * 16 + lq) * 64 + kc * 32 + lg * 8]);
#pragma unroll
      for (int nf = 0; nf < 4; ++nf)
        bfr[nf] = *(const bf16x8*)(&Bs[(wc * 64 + nf * 16 + lq) * 64 + kc * 32 + lg * 8]);
#pragma unroll
      for (int mf = 0; mf < 4; ++mf)
#pragma unroll
        for (int nf = 0; nf < 4; ++nf)
          acc[mf][nf] = MFMA16(af[mf], bfr[nf], acc[mf][nf]);
    }
  }

  float bvv[4];
#pragma unroll
  for (int nf = 0; nf < 4; ++nf) bvv[nf] = bias[col0 + wc * 64 + nf * 16 + lq];

#pragma unroll
  for (int mf = 0; mf < 4; ++mf) {
#pragma unroll
    for (int nf = 0; nf < 4; ++nf) {
      const int col = col0 + wc * 64 + nf * 16 + lq;
      const int h = col >> 6, d = col & 63;
      if (z < 2) {  // rope scatter to [B,H,L,64]
        ushort_t* o = z == 0 ? Qh : Kh;
#pragma unroll
        for (int u = 0; u < 4; ++u) {
          const int row = row0 + wr * 64 + mf * 16 + 4 * lg + u;
          const int bb = row >> 11, l = row & 2047;
          float val = acc[mf][nf][u] + bvv[nf];
          float2 cs = rope[l * 32 + (d >> 1)];
          float p = __shfl_xor(val, 1, 64);
          val = ((d & 1) ? (val * cs.x + p * cs.y) : (val * cs.x - p * cs.y)) * scale;
          o[(((size_t)bb * 16 + h) * 2048 + l) * 64 + d] = f2bf(val);
        }
      } else {  // V^T direct: VhT[(bh*64 + d)*2048 + l]
        const int row = row0 + wr * 64 + mf * 16 + 4 * lg;
        const int bb = row >> 11, l0 = row & 2047;
        u16x4 o;
#pragma unroll
        for (int u = 0; u < 4; ++u) o[u] = f2bf(acc[mf][nf][u] + bvv[nf]);
        *(u16x4*)(VhT + (((size_t)bb * 16 + h) * 64 + d) * 2048 + l0) = o;
      }
    }
  }
}

// ---------------------------------------------------------------- Wo GEMM -> f32 out
__global__ __launch_bounds__(256, 4)
void gemm_out(const ushort_t* __restrict__ Am, const ushort_t* __restrict__ Wm,
              const float* __restrict__ bias, float* __restrict__ outp) {
  constexpr int K = 1024;
  __shared__ ushort_t As[128 * 64];
  __shared__ ushort_t Bs[128 * 64];

  const int b = blockIdx.x;
  const int xcd = b & 7, i2 = b >> 3;
  const int bx = i2 & 7;
  const int by = ((i2 >> 3) & 7) * 8 + xcd;

  const int t = threadIdx.x;
  const int lane = t & 63, w = t >> 6;
  const int lq = lane & 15, lg = lane >> 4;
  const int wr = w >> 1, wc = w & 1;
  const int row0 = by * 128;
  const int col0 = bx * 128;

  f32x4 acc[4][4] = {};
  for (int kt = 0; kt < K / 64; ++kt) {
    __syncthreads();
#pragma unroll
    for (int it = 0; it < 4; ++it) {
      const int s = it * 256 + t;
      const int ldsoff = (it * 256 + w * 64) * 8;
      GLDS(Am + (size_t)(row0 + (s >> 3)) * K + kt * 64 + (s & 7) * 8, &As[ldsoff]);
      GLDS(Wm + (size_t)(col0 + (s >> 3)) * K + kt * 64 + (s & 7) * 8, &Bs[ldsoff]);
    }
    __syncthreads();
#pragma unroll
    for (int kc = 0; kc < 2; ++kc) {
      bf16x8 af[4], bfr[4];
#pragma unroll
      for (int mf = 0; mf < 4; ++mf)
        af[mf] = *(const bf16x8*)(&As[(wr * 64 + mf * 16 + lq) * 64 + kc * 32 + lg * 8]);
#pragma unroll
      for (int nf = 0; nf < 4; ++nf)
        bfr[nf] = *(const bf16x8*)(&Bs[(wc * 64 + nf * 16 + lq) * 64 + kc * 32 + lg * 8]);
#pragma unroll
      for (int mf = 0; mf < 4; ++mf)
#pragma unroll
        for (int nf = 0; nf < 4; ++nf)
          acc[mf][nf] = MFMA16(af[mf], bfr[nf], acc[mf][nf]);
    }
  }

  float bvv[4];
#pragma unroll
  for (int nf = 0; nf < 4; ++nf) bvv[nf] = bias[col0 + wc * 64 + nf * 16 + lq];

#pragma unroll
  for (int mf = 0; mf < 4; ++mf) {
#pragma unroll
    for (int nf = 0; nf < 4; ++nf) {
      const int col = col0 + wc * 64 + nf * 16 + lq;
#pragma unroll
      for (int u = 0; u < 4; ++u) {
        const int row = row0 + wr * 64 + mf * 16 + 4 * lg + u;
        outp[(size_t)row * 1024 + col] = acc[mf][nf][u] + bvv[nf];
      }
    }
  }
}

// ---------------------------------------------------------------- flash attention (causal)
// R10/R14-verified kernel: paired q-tiles, dbuf global_load_lds staging,
// natural-log softmax + defer-max(11) + cvtpk, setprio around MFMA clusters.
__global__ __launch_bounds__(256, 4)
void attn_fwd(const ushort_t* __restrict__ Qh, const ushort_t* __restrict__ Kh,
              const ushort_t* __restrict__ VhT, ushort_t* __restrict__ attn) {
  constexpr int L = 2048;
  __shared__ __align__(16) char KV[2][16384];  // [buf][ K 8KB | V^T 8KB ], XOR-swizzled
  __shared__ __align__(16) char Pl[4][2048];   // per-wave P [16 q][64 kv] bf16, XOR-swizzled
  const int t = threadIdx.x;
  const int lane = t & 63, w = t >> 6;
  const int lq = lane & 15, lg = lane >> 4;

  const int fid = blockIdx.y * 16 + blockIdx.x;  // XCD swizzle: one bh per XCD group
  const int bh = (fid & 7) * 8 + (fid >> 7);
  const int i = (fid >> 3) & 15;
  const int lo = i, hi = 31 - i, nt = 32 - i;
  const int qlo = lo * 64 + w * 16 + lq;
  const int qhi = hi * 64 + w * 16 + lq;

  bf16x8 qfl[2], qfh[2];
  {
    const ushort_t* p = Qh + ((size_t)bh * L + qlo) * 64 + lg * 8;
    qfl[0] = *(const bf16x8*)p;
    qfl[1] = *(const bf16x8*)(p + 32);
    const ushort_t* p2 = Qh + ((size_t)bh * L + qhi) * 64 + lg * 8;
    qfh[0] = *(const bf16x8*)p2;
    qfh[1] = *(const bf16x8*)(p2 + 32);
  }

  float ml = -1e30f, ll = 0.0f, mh = -1e30f, lh = 0.0f;
  f32x4 otl[4] = {}, oth[4] = {};
  char* const pw = Pl[w];

  auto STAGE = [&](int bb, int kb) {
    const int kv0 = kb * 64;
#pragma unroll
    for (int it = 0; it < 2; ++it) {
      const int s = it * 256 + t;
      const int r = s >> 3;
      const int sc = (s ^ r) & 7;  // inverse swizzle on the global source (G21)
      char* base = KV[bb] + (it * 256 + w * 64) * 16;
      GLDS(Kh + ((size_t)bh * L + kv0 + r) * 64 + sc * 8, base);
      GLDS(VhT + ((size_t)bh * 64 + r) * L + kv0 + sc * 8, base + 8192);
    }
  };

  auto TILE = [&](int bb, int kb, int diagkb, int qrow, const bf16x8* qf, float& m,
                  float& lsum, f32x4* ot) {
    const char* Kb = KV[bb];
    const char* Vb = KV[bb] + 8192;
    f32x4 st[4];
    __builtin_amdgcn_s_setprio(1);
#pragma unroll
    for (int kf = 0; kf < 4; ++kf) {
      f32x4 c = {};
#pragma unroll
      for (int kc = 0; kc < 2; ++kc) {
        const int r = kf * 16 + lq;
        const int byte = (r * 128 + kc * 64 + lg * 16) ^ ((r & 7) << 4);
        c = MFMA16(*(const bf16x8*)(Kb + byte), qf[kc], c);
      }
      st[kf] = c;
    }
    __builtin_amdgcn_s_setprio(0);
    if (kb == diagkb) {
      const int kv0 = kb * 64;
#pragma unroll
      for (int kf = 0; kf < 4; ++kf)
#pragma unroll
        for (int u = 0; u < 4; ++u)
          if (kv0 + kf * 16 + 4 * lg + u > qrow) st[kf][u] = -1e30f;
    }
    // row max (q = lq), reduce across lg groups
    float pmax = st[0][0];
#pragma unroll
    for (int kf = 0; kf < 4; ++kf)
#pragma unroll
      for (int u = 0; u < 4; ++u) pmax = fmaxf(pmax, st[kf][u]);
    pmax = fmaxf(pmax, __shfl_xor(pmax, 16, 64));
    pmax = fmaxf(pmax, __shfl_xor(pmax, 32, 64));
    // defer-max (T13): skip O/l rescale while max growth < 11
    if (!__all(pmax <= m + 11.0f)) {
      const float mn = fmaxf(m, pmax);
      const float c2 = __expf(m - mn);
      lsum *= c2;
#pragma unroll
      for (int df = 0; df < 4; ++df) ot[df] *= c2;
      m = mn;
    }
    float psum = 0.0f;
#pragma unroll
    for (int kf = 0; kf < 4; ++kf) {
      const float p0 = __expf(st[kf][0] - m);
      const float p1 = __expf(st[kf][1] - m);
      const float p2 = __expf(st[kf][2] - m);
      const float p3 = __expf(st[kf][3] - m);
      psum += (p0 + p1) + (p2 + p3);
      uint2 pk;
      pk.x = cvtpk_bf16(p0, p1);
      pk.y = cvtpk_bf16(p2, p3);
      const int byte = (lq * 128 + kf * 32 + lg * 8) ^ ((lq & 7) << 4);
      *(uint2*)(pw + byte) = pk;
    }
    psum += __shfl_xor(psum, 16, 64);
    psum += __shfl_xor(psum, 32, 64);
    lsum += psum;
    asm volatile("s_waitcnt lgkmcnt(0)" ::: "memory");
    // O^T[d][q] += V^T . P^T
    __builtin_amdgcn_s_setprio(1);
#pragma unroll
    for (int df = 0; df < 4; ++df) {
#pragma unroll
      for (int kc = 0; kc < 2; ++kc) {
        const int r = df * 16 + lq;
        const int byte = (r * 128 + kc * 64 + lg * 16) ^ ((r & 7) << 4);
        const int pbyte = (lq * 128 + kc * 64 + lg * 16) ^ ((lq & 7) << 4);
        ot[df] = MFMA16(*(const bf16x8*)(Vb + byte), *(const bf16x8*)(pw + pbyte), ot[df]);
      }
    }
    __builtin_amdgcn_s_setprio(0);
  };

  STAGE(0, 0);
  __syncthreads();
  int cur = 0;
  for (int kb = 0; kb < nt; ++kb) {
    if (kb + 1 < nt) STAGE(cur ^ 1, kb + 1);  // prefetch overlaps both tiles' compute
    TILE(cur, kb, hi, qhi, qfh, mh, lh, oth);
    if (kb <= lo) TILE(cur, kb, lo, qlo, qfl, ml, ll, otl);
    __syncthreads();
    cur ^= 1;
  }

  const int b = bh >> 4, h = bh & 15;
  {
    const float inv = 1.0f / lh;
#pragma unroll
    for (int df = 0; df < 4; ++df) {
      u16x4 o;
#pragma unroll
      for (int u = 0; u < 4; ++u) o[u] = f2bf(oth[df][u] * inv);
      *(u16x4*)(attn + ((size_t)b * L + qhi) * 1024 + h * 64 + df * 16 + 4 * lg) = o;
    }
  }
  {
    const float inv = 1.0f / ll;
#pragma unroll
    for (int df = 0; df < 4; ++df) {
      u16x4 o;
#pragma unroll
      for (int u = 0; u < 4; ++u) o[u] = f2bf(otl[df][u] * inv);
      *(u16x4*)(attn + ((size_t)b * L + qlo) * 1024 + h * 64 + df * 16 + 4 * lg) = o;
    }
  }
}

// ---------------------------------------------------------------- launcher
extern "C" void kernel_launch(void* const* d_in, const int* in_sizes, int n_in,
                              void* d_out, int out_size, void* d_ws, size_t ws_size,
                              hipStream_t stream) {
  const float* q = (const float*)d_in[0];
  const float* k = (const float*)d_in[1];
  const float* v = (const float*)d_in[2];
  const float* Wq = (const float*)d_in[3];
  const float* bq = (const float*)d_in[4];
  const float* Wk = (const float*)d_in[5];
  const float* bk = (const float*)d_in[6];
  const float* Wv = (const float*)d_in[7];
  const float* bv = (const float*)d_in[8];
  const float* Wo = (const float*)d_in[9];
  const float* bo = (const float*)d_in[10];

  char* ws = (char*)d_ws;
  const size_t MB = 1ull << 20;
  ushort_t* qb = (ushort_t*)(ws + 0 * MB);    // 16MB (reused as attn after Q GEMM)
  ushort_t* kb = (ushort_t*)(ws + 16 * MB);   // 16MB
  ushort_t* vb = (ushort_t*)(ws + 32 * MB);   // 16MB
  ushort_t* Wqb = (ushort_t*)(ws + 48 * MB);  // 2MB
  ushort_t* Wkb = (ushort_t*)(ws + 50 * MB);  // 2MB
  ushort_t* Wvb = (ushort_t*)(ws + 52 * MB);  // 2MB
  ushort_t* Wob = (ushort_t*)(ws + 54 * MB);  // 2MB
  float2* rope = (float2*)(ws + 56 * MB);     // 512KB
  ushort_t* Qh = (ushort_t*)(ws + 57 * MB);   // 16MB
  ushort_t* Kh = (ushort_t*)(ws + 73 * MB);   // 16MB
  ushort_t* VhT = (ushort_t*)(ws + 89 * MB);  // 16MB
  ushort_t* attnb = qb;                       // alias: qb dead after fused QKV GEMM

  prep<<<14592, 256, 0, stream>>>(q, k, v, Wq, Wk, Wv, Wo, qb, kb, vb, Wqb, Wkb, Wvb,
                                  Wob, rope);

  gemm_qkv<<<1536, 256, 0, stream>>>(qb, kb, vb, Wqb, Wkb, Wvb, bq, bk, bv, Qh, Kh, VhT,
                                     rope);

  attn_fwd<<<dim3(16, 64), 256, 0, stream>>>(Qh, Kh, VhT, attnb);

  gemm_out<<<512, 256, 0, stream>>>(attnb, Wob, bo, (float*)d_out);

  (void)in_sizes; (void)n_in; (void)out_size; (void)ws_size;
}